// Round 2
// baseline (338.733 us; speedup 1.0000x reference)
//
#include <hip/hip_runtime.h>

#define NB   8
#define TSRC 4096
#define TTGT 2048
#define CH   1024   // C_IN == C_OUT

typedef __attribute__((ext_vector_type(4))) float  f32x4;
typedef __attribute__((ext_vector_type(8))) __bf16 bf16x8;
typedef __attribute__((ext_vector_type(4))) __bf16 bf16x4;

// ---------------- kernel 1: ragged sizes (src_sizes[0..7], tgt_sizes[8..15]) --------
__global__ __launch_bounds__(256) void sizes_kernel(const int* __restrict__ src_mask,
                                                    const int* __restrict__ tgt_mask,
                                                    int* __restrict__ sizes) {
  const int id = blockIdx.x;  // 0..7 -> src, 8..15 -> tgt
  const int b  = id & 7;
  const int* m = (id < 8) ? (src_mask + (size_t)b * TSRC) : (tgt_mask + (size_t)b * TTGT);
  const int T  = (id < 8) ? TSRC : TTGT;
  int s = 0;
  for (int i = threadIdx.x; i < T; i += 256) s += m[i];
#pragma unroll
  for (int off = 32; off > 0; off >>= 1) s += __shfl_down(s, off);
  __shared__ int red[4];
  if ((threadIdx.x & 63) == 0) red[threadIdx.x >> 6] = s;
  __syncthreads();
  if (threadIdx.x == 0) sizes[id] = red[0] + red[1] + red[2] + red[3];
}

// ---------------- kernel 2: y = tgt @ W^T + bias (bf16 MFMA, 128x128x32 tiles) ------
// A = tgt [M=NB*TTGT, K=CH] row-major; B = W [N=CH, K=CH] row-major (B^T input / NT GEMM).
// 256 threads = 4 waves in 2x2; each wave computes 64x64 = 4x4 tiles of 16x16.
__global__ __launch_bounds__(256, 2) void gemm_kernel(const float* __restrict__ tgt,
                                                      const float* __restrict__ W,
                                                      const float* __restrict__ bias,
                                                      const int* __restrict__ sizes,
                                                      float* __restrict__ y) {
  const int n0 = blockIdx.x * 128;
  const int m0 = blockIdx.y * 128;          // row in flattened [NB*TTGT]
  const int b  = m0 >> 11;                  // / TTGT
  const int t0 = m0 & (TTGT - 1);
  if (t0 >= sizes[8 + b]) return;           // these rows are never gathered

  __shared__ __bf16 As[128 * 32];           // row stride 32 bf16 (64 B)
  __shared__ __bf16 Bs[128 * 32];

  const int tid  = threadIdx.x;
  const int kc   = tid & 7;                 // which float4 within the 32-wide k-chunk
  const int r0   = tid >> 3;                // 0..31
  const int lane = tid & 63;
  const int wave = tid >> 6;
  const int wm   = (wave >> 1) * 64;
  const int wn   = (wave & 1) * 64;
  const int lr   = lane & 15;
  const int quad = lane >> 4;

  f32x4 acc[4][4];
  const f32x4 z = {0.f, 0.f, 0.f, 0.f};
#pragma unroll
  for (int i = 0; i < 4; ++i)
#pragma unroll
    for (int j = 0; j < 4; ++j) acc[i][j] = z;

  const float* gA = tgt + (size_t)m0 * CH;
  const float* gB = W + (size_t)n0 * CH;

  for (int kb = 0; kb < CH; kb += 32) {
    // stage 128x32 f32 -> bf16 into LDS for A and B (convert on the fly)
#pragma unroll
    for (int rr = 0; rr < 4; ++rr) {
      const int r = r0 + rr * 32;
      const float4 va = *(const float4*)(gA + (size_t)r * CH + kb + kc * 4);
      const float4 vb = *(const float4*)(gB + (size_t)r * CH + kb + kc * 4);
      bf16x4 ua = {(__bf16)va.x, (__bf16)va.y, (__bf16)va.z, (__bf16)va.w};
      bf16x4 ub = {(__bf16)vb.x, (__bf16)vb.y, (__bf16)vb.z, (__bf16)vb.w};
      *(bf16x4*)(As + r * 32 + kc * 4) = ua;
      *(bf16x4*)(Bs + r * 32 + kc * 4) = ub;
    }
    __syncthreads();
    bf16x8 af[4], bfv[4];
#pragma unroll
    for (int i = 0; i < 4; ++i) af[i] = *(const bf16x8*)(As + (wm + i * 16 + lr) * 32 + quad * 8);
#pragma unroll
    for (int j = 0; j < 4; ++j) bfv[j] = *(const bf16x8*)(Bs + (wn + j * 16 + lr) * 32 + quad * 8);
#pragma unroll
    for (int i = 0; i < 4; ++i)
#pragma unroll
      for (int j = 0; j < 4; ++j)
        acc[i][j] = __builtin_amdgcn_mfma_f32_16x16x32_bf16(af[i], bfv[j], acc[i][j], 0, 0, 0);
    __syncthreads();
  }

  // epilogue: C/D layout col = lane&15, row = quad*4 + reg
#pragma unroll
  for (int i = 0; i < 4; ++i) {
    const int mrow = m0 + wm + i * 16 + quad * 4;
#pragma unroll
    for (int j = 0; j < 4; ++j) {
      const int ncol = n0 + wn + j * 16 + lr;
      const float bv = bias[ncol];
      float* yp = y + (size_t)mrow * CH + ncol;
#pragma unroll
      for (int r = 0; r < 4; ++r) yp[(size_t)r * CH] = acc[i][j][r] + bv;
    }
  }
}

// ---------------- kernel 3: gather + LayerNorm + scatter + mask passthrough --------
__global__ __launch_bounds__(256) void ln_kernel(const float* __restrict__ y,
                                                 const int* __restrict__ sizes,
                                                 const int* __restrict__ src_mask,
                                                 const float* __restrict__ g,
                                                 const float* __restrict__ be,
                                                 float* __restrict__ out,
                                                 float* __restrict__ mask_out) {
  const int bx = blockIdx.x;
  const int b  = bx >> 12;           // / TSRC
  const int j  = bx & (TSRC - 1);
  const int t  = threadIdx.x;
  const int ss = sizes[b];
  const int tg = sizes[8 + b];
  const bool valid = j < ss;

  float4 v = make_float4(0.f, 0.f, 0.f, 0.f);
  if (valid) {
    const int den = (ss > 0) ? ss : 1;
    int ii = (int)(((long long)j * (long long)tg) / den);
    const int hi = ((tg > 1) ? tg : 1) - 1;
    if (ii > hi) ii = hi;
    if (ii < 0) ii = 0;
    v = ((const float4*)(y + ((size_t)b * TTGT + ii) * CH))[t];
  }
  float s  = v.x + v.y + v.z + v.w;
  float sq = v.x * v.x + v.y * v.y + v.z * v.z + v.w * v.w;
#pragma unroll
  for (int off = 32; off > 0; off >>= 1) {
    s  += __shfl_down(s, off);
    sq += __shfl_down(sq, off);
  }
  __shared__ float red[8];
  __shared__ float stats[2];
  if ((t & 63) == 0) { red[t >> 6] = s; red[4 + (t >> 6)] = sq; }
  __syncthreads();
  if (t == 0) {
    const float S  = red[0] + red[1] + red[2] + red[3];
    const float Q  = red[4] + red[5] + red[6] + red[7];
    const float mu = S * (1.0f / CH);
    float var = Q * (1.0f / CH) - mu * mu;
    var = fmaxf(var, 0.0f);
    stats[0] = mu;
    stats[1] = rsqrtf(var + 1e-5f);
  }
  __syncthreads();
  const float mu = stats[0], rs = stats[1];
  const float4 gg = ((const float4*)g)[t];
  const float4 bb = ((const float4*)be)[t];
  float4 o;
  o.x = (v.x - mu) * rs * gg.x + bb.x;
  o.y = (v.y - mu) * rs * gg.y + bb.y;
  o.z = (v.z - mu) * rs * gg.z + bb.z;
  o.w = (v.w - mu) * rs * gg.w + bb.w;
  ((float4*)(out + ((size_t)b * TSRC + j) * CH))[t] = o;
  if (t == 0) mask_out[bx] = (float)src_mask[bx];
}

// ---------------- fallback: fully self-contained, no workspace needed ---------------
__global__ __launch_bounds__(256) void fallback_kernel(const float* __restrict__ tgt,
                                                       const int* __restrict__ src_mask,
                                                       const int* __restrict__ tgt_mask,
                                                       const float* __restrict__ W,
                                                       const float* __restrict__ bias,
                                                       const float* __restrict__ g,
                                                       const float* __restrict__ be,
                                                       float* __restrict__ out,
                                                       float* __restrict__ mask_out) {
  const int bx = blockIdx.x;
  const int b  = bx >> 12;
  const int j  = bx & (TSRC - 1);
  const int t  = threadIdx.x;
  int s1 = 0, s2 = 0;
  for (int i = t; i < TSRC; i += 256) s1 += src_mask[(size_t)b * TSRC + i];
  for (int i = t; i < TTGT; i += 256) s2 += tgt_mask[(size_t)b * TTGT + i];
#pragma unroll
  for (int off = 32; off > 0; off >>= 1) { s1 += __shfl_down(s1, off); s2 += __shfl_down(s2, off); }
  __shared__ int ired[8];
  if ((t & 63) == 0) { ired[t >> 6] = s1; ired[4 + (t >> 6)] = s2; }
  __syncthreads();
  const int ss = ired[0] + ired[1] + ired[2] + ired[3];
  const int tg = ired[4] + ired[5] + ired[6] + ired[7];
  const bool valid = j < ss;
  int ii = 0;
  if (valid) {
    const int den = (ss > 0) ? ss : 1;
    ii = (int)(((long long)j * (long long)tg) / den);
    const int hi = ((tg > 1) ? tg : 1) - 1;
    if (ii > hi) ii = hi;
    if (ii < 0) ii = 0;
  }
  __shared__ float trow[CH];
  const float* tr = tgt + ((size_t)b * TTGT + ii) * CH;
  for (int i = t; i < CH; i += 256) trow[i] = valid ? tr[i] : 0.0f;
  __syncthreads();
  float4 v = make_float4(0.f, 0.f, 0.f, 0.f);
  if (valid) {
    float a0 = 0.f, a1 = 0.f, a2 = 0.f, a3 = 0.f;
    const float* w0 = W + (size_t)(4 * t + 0) * CH;
    const float* w1 = W + (size_t)(4 * t + 1) * CH;
    const float* w2 = W + (size_t)(4 * t + 2) * CH;
    const float* w3 = W + (size_t)(4 * t + 3) * CH;
    for (int k = 0; k < CH; ++k) {
      const float x = trow[k];
      a0 += x * w0[k]; a1 += x * w1[k]; a2 += x * w2[k]; a3 += x * w3[k];
    }
    v.x = a0 + bias[4 * t + 0];
    v.y = a1 + bias[4 * t + 1];
    v.z = a2 + bias[4 * t + 2];
    v.w = a3 + bias[4 * t + 3];
  }
  float s  = v.x + v.y + v.z + v.w;
  float sq = v.x * v.x + v.y * v.y + v.z * v.z + v.w * v.w;
#pragma unroll
  for (int off = 32; off > 0; off >>= 1) {
    s  += __shfl_down(s, off);
    sq += __shfl_down(sq, off);
  }
  __shared__ float red[8];
  __shared__ float stats[2];
  if ((t & 63) == 0) { red[t >> 6] = s; red[4 + (t >> 6)] = sq; }
  __syncthreads();
  if (t == 0) {
    const float S  = red[0] + red[1] + red[2] + red[3];
    const float Q  = red[4] + red[5] + red[6] + red[7];
    const float mu = S * (1.0f / CH);
    float var = Q * (1.0f / CH) - mu * mu;
    var = fmaxf(var, 0.0f);
    stats[0] = mu;
    stats[1] = rsqrtf(var + 1e-5f);
  }
  __syncthreads();
  const float mu = stats[0], rs = stats[1];
  const float4 gg = ((const float4*)g)[t];
  const float4 bb = ((const float4*)be)[t];
  float4 o;
  o.x = (v.x - mu) * rs * gg.x + bb.x;
  o.y = (v.y - mu) * rs * gg.y + bb.y;
  o.z = (v.z - mu) * rs * gg.z + bb.z;
  o.w = (v.w - mu) * rs * gg.w + bb.w;
  ((float4*)(out + ((size_t)b * TSRC + j) * CH))[t] = o;
  if (t == 0) mask_out[bx] = (float)src_mask[bx];
}

extern "C" void kernel_launch(void* const* d_in, const int* in_sizes, int n_in,
                              void* d_out, int out_size, void* d_ws, size_t ws_size,
                              hipStream_t stream) {
  (void)in_sizes; (void)n_in; (void)out_size;
  // setup_inputs order: src, src_mask, tgt, tgt_mask, conv_w, conv_b, ln_g, ln_b
  const int*   src_mask = (const int*)d_in[1];
  const float* tgt      = (const float*)d_in[2];
  const int*   tgt_mask = (const int*)d_in[3];
  const float* conv_w   = (const float*)d_in[4];
  const float* conv_b   = (const float*)d_in[5];
  const float* ln_g     = (const float*)d_in[6];
  const float* ln_b     = (const float*)d_in[7];

  float* out      = (float*)d_out;
  float* mask_out = out + (size_t)NB * TSRC * CH;   // second tuple element, as f32

  const size_t need = 256 + (size_t)NB * TTGT * CH * sizeof(float);
  if (ws_size >= need) {
    int*   sizes = (int*)d_ws;
    float* y     = (float*)((char*)d_ws + 256);
    sizes_kernel<<<16, 256, 0, stream>>>(src_mask, tgt_mask, sizes);
    gemm_kernel<<<dim3(CH / 128, (NB * TTGT) / 128), 256, 0, stream>>>(tgt, conv_w, conv_b, sizes, y);
    ln_kernel<<<NB * TSRC, 256, 0, stream>>>(y, sizes, src_mask, ln_g, ln_b, out, mask_out);
  } else {
    fallback_kernel<<<NB * TSRC, 256, 0, stream>>>(tgt, src_mask, tgt_mask, conv_w, conv_b,
                                                   ln_g, ln_b, out, mask_out);
  }
}

// Round 3
// 320.498 us; speedup vs baseline: 1.0569x; 1.0569x over previous
//
#include <hip/hip_runtime.h>

#define NB   8
#define TSRC 4096
#define TTGT 2048
#define CH   1024   // C_IN == C_OUT
#define BK   64

typedef __attribute__((ext_vector_type(4))) float  f32x4;
typedef __attribute__((ext_vector_type(8))) __bf16 bf16x8;
typedef __attribute__((ext_vector_type(4))) __bf16 bf16x4;

__device__ __forceinline__ void async16(const void* g, void* l) {
  __builtin_amdgcn_global_load_lds((const __attribute__((address_space(1))) void*)g,
                                   (__attribute__((address_space(3))) void*)l, 16, 0, 0);
}

// ---------------- kernel 1: ragged sizes (src_sizes[0..7], tgt_sizes[8..15]) --------
__global__ __launch_bounds__(256) void sizes_kernel(const int* __restrict__ src_mask,
                                                    const int* __restrict__ tgt_mask,
                                                    int* __restrict__ sizes) {
  const int id = blockIdx.x;  // 0..7 -> src, 8..15 -> tgt
  const int b  = id & 7;
  const int* m = (id < 8) ? (src_mask + (size_t)b * TSRC) : (tgt_mask + (size_t)b * TTGT);
  const int T  = (id < 8) ? TSRC : TTGT;
  int s = 0;
  for (int i = threadIdx.x; i < T; i += 256) s += m[i];
#pragma unroll
  for (int off = 32; off > 0; off >>= 1) s += __shfl_down(s, off);
  __shared__ int red[4];
  if ((threadIdx.x & 63) == 0) red[threadIdx.x >> 6] = s;
  __syncthreads();
  if (threadIdx.x == 0) sizes[id] = red[0] + red[1] + red[2] + red[3];
}

// ---------------- kernel 2: f32 -> bf16 convert (tgt rows + W rows) + mask out ------
__global__ __launch_bounds__(256) void convert_kernel(const float* __restrict__ tgt,
                                                      const float* __restrict__ W,
                                                      const int* __restrict__ sizes,
                                                      const int* __restrict__ src_mask,
                                                      __bf16* __restrict__ Abf,
                                                      __bf16* __restrict__ Wbf,
                                                      float* __restrict__ mask_out) {
  const int bx = blockIdx.x;
  const int t  = threadIdx.x;
  if (bx < (NB * TSRC) / 256) {
    const int i = bx * 256 + t;
    mask_out[i] = (float)src_mask[i];
  }
  if (bx < NB * TTGT) {   // a tgt row
    const int b = bx >> 11;
    const int r = bx & (TTGT - 1);
    if (r >= sizes[8 + b]) return;   // never gathered; leave unconverted
    const float4 v = ((const float4*)(tgt + (size_t)bx * CH))[t];
    bf16x4 u = {(__bf16)v.x, (__bf16)v.y, (__bf16)v.z, (__bf16)v.w};
    *(bf16x4*)(Abf + (size_t)bx * CH + t * 4) = u;
  } else {                // a W row
    const int r = bx - NB * TTGT;
    const float4 v = ((const float4*)(W + (size_t)r * CH))[t];
    bf16x4 u = {(__bf16)v.x, (__bf16)v.y, (__bf16)v.z, (__bf16)v.w};
    *(bf16x4*)(Wbf + (size_t)r * CH + t * 4) = u;
  }
}

// ---------------- kernel 3: y = A @ W^T + bias, bf16 in, bf16 out (m97-style) -------
// A [M=NB*TTGT, K=CH] bf16 row-major; Wbf [N=CH, K=CH] bf16 row-major (NT GEMM).
// 128x128 tile, BK=64, global_load_lds width-16 staging, 4 waves in 2x2.
__global__ __launch_bounds__(256) void gemm_kernel(const __bf16* __restrict__ A,
                                                   const __bf16* __restrict__ Bw,
                                                   const float* __restrict__ bias,
                                                   const int* __restrict__ sizes,
                                                   __bf16* __restrict__ y) {
  const int n0 = blockIdx.x * 128;
  const int m0 = blockIdx.y * 128;
  const int b  = m0 >> 11;
  const int t0 = m0 & (TTGT - 1);
  if (t0 >= sizes[8 + b]) return;   // rows never gathered

  __shared__ __bf16 As[128 * BK];   // 16 KB
  __shared__ __bf16 Bs[128 * BK];   // 16 KB

  const int tid  = threadIdx.x;
  const int lane = tid & 63;
  const int wave = tid >> 6;
  const int wm   = (wave >> 1) * 64;
  const int wn   = (wave & 1) * 64;
  const int lr   = lane & 15;
  const int quad = lane >> 4;

  // staging: thread t, issue q -> LDS elem q*2048 + t*8  (= row (q*32 + t/8), col (t%8)*8)
  const int srow = tid >> 3;
  const int scol = (tid & 7) * 8;
  const __bf16* gA = A  + ((size_t)(m0 + srow)) * CH + scol;
  const __bf16* gB = Bw + ((size_t)(n0 + srow)) * CH + scol;
  __bf16* lA = As + tid * 8;
  __bf16* lB = Bs + tid * 8;

  f32x4 acc[4][4];
  const f32x4 z = {0.f, 0.f, 0.f, 0.f};
#pragma unroll
  for (int i = 0; i < 4; ++i)
#pragma unroll
    for (int j = 0; j < 4; ++j) acc[i][j] = z;

  for (int kb = 0; kb < CH; kb += BK) {
#pragma unroll
    for (int q = 0; q < 4; ++q) {
      async16(gA + (size_t)q * 32 * CH + kb, lA + q * 2048);
      async16(gB + (size_t)q * 32 * CH + kb, lB + q * 2048);
    }
    __syncthreads();   // drains vmcnt (async LDS loads) + lgkm
#pragma unroll
    for (int ko = 0; ko < 2; ++ko) {
      bf16x8 af[4], bf[4];
#pragma unroll
      for (int i = 0; i < 4; ++i)
        af[i] = *(const bf16x8*)(As + (wm + i * 16 + lr) * BK + ko * 32 + quad * 8);
#pragma unroll
      for (int j = 0; j < 4; ++j)
        bf[j] = *(const bf16x8*)(Bs + (wn + j * 16 + lr) * BK + ko * 32 + quad * 8);
#pragma unroll
      for (int i = 0; i < 4; ++i)
#pragma unroll
        for (int j = 0; j < 4; ++j)
          acc[i][j] = __builtin_amdgcn_mfma_f32_16x16x32_bf16(af[i], bf[j], acc[i][j], 0, 0, 0);
    }
    __syncthreads();
  }

  // epilogue: C/D layout col = lane&15, row = quad*4 + reg; store bf16
#pragma unroll
  for (int i = 0; i < 4; ++i) {
    const int mrow = m0 + wm + i * 16 + quad * 4;
#pragma unroll
    for (int j = 0; j < 4; ++j) {
      const int ncol = n0 + wn + j * 16 + lr;
      const float bv = bias[ncol];
      __bf16* yp = y + (size_t)mrow * CH + ncol;
#pragma unroll
      for (int r = 0; r < 4; ++r) yp[(size_t)r * CH] = (__bf16)(acc[i][j][r] + bv);
    }
  }
}

// ---------------- kernel 4: gather + LayerNorm, wave-per-row (no barriers) ----------
__global__ __launch_bounds__(256) void ln_kernel(const __bf16* __restrict__ y,
                                                 const int* __restrict__ sizes,
                                                 const float* __restrict__ g,
                                                 const float* __restrict__ be,
                                                 float* __restrict__ out) {
  const int wid = (blockIdx.x * 256 + threadIdx.x) >> 6;  // 0..8191
  const int l   = threadIdx.x & 63;
#pragma unroll
  for (int rr = 0; rr < 4; ++rr) {
    const int row = wid + rr * 8192;        // 0..32767
    const int b   = row >> 12;
    const int j   = row & (TSRC - 1);
    const int ss  = sizes[b];
    const int tg  = sizes[8 + b];
    float v[16];
    if (j < ss) {
      const int den = (ss > 0) ? ss : 1;
      int ii = (int)(((long long)j * (long long)tg) / den);
      const int hi = ((tg > 1) ? tg : 1) - 1;
      ii = (ii > hi) ? hi : ((ii < 0) ? 0 : ii);
      const __bf16* yr = y + ((size_t)b * TTGT + ii) * CH;
      const bf16x8 u0 = *(const bf16x8*)(yr + l * 8);
      const bf16x8 u1 = *(const bf16x8*)(yr + 512 + l * 8);
#pragma unroll
      for (int k = 0; k < 8; ++k) { v[k] = (float)u0[k]; v[8 + k] = (float)u1[k]; }
    } else {
#pragma unroll
      for (int k = 0; k < 16; ++k) v[k] = 0.f;
    }
    float s = 0.f, q = 0.f;
#pragma unroll
    for (int k = 0; k < 16; ++k) { s += v[k]; q += v[k] * v[k]; }
#pragma unroll
    for (int off = 32; off > 0; off >>= 1) {
      s += __shfl_xor(s, off);
      q += __shfl_xor(q, off);
    }
    const float mu = s * (1.0f / CH);
    float var = q * (1.0f / CH) - mu * mu;
    var = fmaxf(var, 0.0f);
    const float rs = rsqrtf(var + 1e-5f);
    float* orow = out + (size_t)row * CH;
#pragma unroll
    for (int h = 0; h < 2; ++h) {
      const int base = h * 512 + l * 8;
      const float4 g0 = *(const float4*)(g + base);
      const float4 g1 = *(const float4*)(g + base + 4);
      const float4 b0 = *(const float4*)(be + base);
      const float4 b1 = *(const float4*)(be + base + 4);
      float4 o0, o1;
      o0.x = (v[h * 8 + 0] - mu) * rs * g0.x + b0.x;
      o0.y = (v[h * 8 + 1] - mu) * rs * g0.y + b0.y;
      o0.z = (v[h * 8 + 2] - mu) * rs * g0.z + b0.z;
      o0.w = (v[h * 8 + 3] - mu) * rs * g0.w + b0.w;
      o1.x = (v[h * 8 + 4] - mu) * rs * g1.x + b1.x;
      o1.y = (v[h * 8 + 5] - mu) * rs * g1.y + b1.y;
      o1.z = (v[h * 8 + 6] - mu) * rs * g1.z + b1.z;
      o1.w = (v[h * 8 + 7] - mu) * rs * g1.w + b1.w;
      *(float4*)(orow + base)     = o0;
      *(float4*)(orow + base + 4) = o1;
    }
  }
}

// =============== middle tier (round-2 kernels, f32 path, ws >= 64MiB only) ==========
__global__ __launch_bounds__(256, 2) void gemm_f32_kernel(const float* __restrict__ tgt,
                                                          const float* __restrict__ W,
                                                          const float* __restrict__ bias,
                                                          const int* __restrict__ sizes,
                                                          float* __restrict__ y) {
  const int n0 = blockIdx.x * 128;
  const int m0 = blockIdx.y * 128;
  const int b  = m0 >> 11;
  const int t0 = m0 & (TTGT - 1);
  if (t0 >= sizes[8 + b]) return;
  __shared__ __bf16 As[128 * 32];
  __shared__ __bf16 Bs[128 * 32];
  const int tid  = threadIdx.x;
  const int kc   = tid & 7;
  const int r0   = tid >> 3;
  const int lane = tid & 63;
  const int wave = tid >> 6;
  const int wm   = (wave >> 1) * 64;
  const int wn   = (wave & 1) * 64;
  const int lr   = lane & 15;
  const int quad = lane >> 4;
  f32x4 acc[4][4];
  const f32x4 z = {0.f, 0.f, 0.f, 0.f};
#pragma unroll
  for (int i = 0; i < 4; ++i)
#pragma unroll
    for (int j = 0; j < 4; ++j) acc[i][j] = z;
  const float* gA = tgt + (size_t)m0 * CH;
  const float* gB = W + (size_t)n0 * CH;
  for (int kb = 0; kb < CH; kb += 32) {
#pragma unroll
    for (int rr = 0; rr < 4; ++rr) {
      const int r = r0 + rr * 32;
      const float4 va = *(const float4*)(gA + (size_t)r * CH + kb + kc * 4);
      const float4 vb = *(const float4*)(gB + (size_t)r * CH + kb + kc * 4);
      bf16x4 ua = {(__bf16)va.x, (__bf16)va.y, (__bf16)va.z, (__bf16)va.w};
      bf16x4 ub = {(__bf16)vb.x, (__bf16)vb.y, (__bf16)vb.z, (__bf16)vb.w};
      *(bf16x4*)(As + r * 32 + kc * 4) = ua;
      *(bf16x4*)(Bs + r * 32 + kc * 4) = ub;
    }
    __syncthreads();
    bf16x8 af[4], bfv[4];
#pragma unroll
    for (int i = 0; i < 4; ++i) af[i] = *(const bf16x8*)(As + (wm + i * 16 + lr) * 32 + quad * 8);
#pragma unroll
    for (int j = 0; j < 4; ++j) bfv[j] = *(const bf16x8*)(Bs + (wn + j * 16 + lr) * 32 + quad * 8);
#pragma unroll
    for (int i = 0; i < 4; ++i)
#pragma unroll
      for (int j = 0; j < 4; ++j)
        acc[i][j] = __builtin_amdgcn_mfma_f32_16x16x32_bf16(af[i], bfv[j], acc[i][j], 0, 0, 0);
    __syncthreads();
  }
#pragma unroll
  for (int i = 0; i < 4; ++i) {
    const int mrow = m0 + wm + i * 16 + quad * 4;
#pragma unroll
    for (int j = 0; j < 4; ++j) {
      const int ncol = n0 + wn + j * 16 + lr;
      const float bv = bias[ncol];
      float* yp = y + (size_t)mrow * CH + ncol;
#pragma unroll
      for (int r = 0; r < 4; ++r) yp[(size_t)r * CH] = acc[i][j][r] + bv;
    }
  }
}

__global__ __launch_bounds__(256) void ln_f32_kernel(const float* __restrict__ y,
                                                     const int* __restrict__ sizes,
                                                     const int* __restrict__ src_mask,
                                                     const float* __restrict__ g,
                                                     const float* __restrict__ be,
                                                     float* __restrict__ out,
                                                     float* __restrict__ mask_out) {
  const int bx = blockIdx.x;
  const int b  = bx >> 12;
  const int j  = bx & (TSRC - 1);
  const int t  = threadIdx.x;
  const int ss = sizes[b];
  const int tg = sizes[8 + b];
  const bool valid = j < ss;
  float4 v = make_float4(0.f, 0.f, 0.f, 0.f);
  if (valid) {
    const int den = (ss > 0) ? ss : 1;
    int ii = (int)(((long long)j * (long long)tg) / den);
    const int hi = ((tg > 1) ? tg : 1) - 1;
    if (ii > hi) ii = hi;
    if (ii < 0) ii = 0;
    v = ((const float4*)(y + ((size_t)b * TTGT + ii) * CH))[t];
  }
  float s  = v.x + v.y + v.z + v.w;
  float sq = v.x * v.x + v.y * v.y + v.z * v.z + v.w * v.w;
#pragma unroll
  for (int off = 32; off > 0; off >>= 1) {
    s  += __shfl_down(s, off);
    sq += __shfl_down(sq, off);
  }
  __shared__ float red[8];
  __shared__ float stats[2];
  if ((t & 63) == 0) { red[t >> 6] = s; red[4 + (t >> 6)] = sq; }
  __syncthreads();
  if (t == 0) {
    const float S  = red[0] + red[1] + red[2] + red[3];
    const float Q  = red[4] + red[5] + red[6] + red[7];
    const float mu = S * (1.0f / CH);
    float var = Q * (1.0f / CH) - mu * mu;
    var = fmaxf(var, 0.0f);
    stats[0] = mu;
    stats[1] = rsqrtf(var + 1e-5f);
  }
  __syncthreads();
  const float mu = stats[0], rs = stats[1];
  const float4 gg = ((const float4*)g)[t];
  const float4 bb = ((const float4*)be)[t];
  float4 o;
  o.x = (v.x - mu) * rs * gg.x + bb.x;
  o.y = (v.y - mu) * rs * gg.y + bb.y;
  o.z = (v.z - mu) * rs * gg.z + bb.z;
  o.w = (v.w - mu) * rs * gg.w + bb.w;
  ((float4*)(out + ((size_t)b * TSRC + j) * CH))[t] = o;
  if (t == 0) mask_out[bx] = (float)src_mask[bx];
}

// ---------------- fallback: fully self-contained, no workspace needed ---------------
__global__ __launch_bounds__(256) void fallback_kernel(const float* __restrict__ tgt,
                                                       const int* __restrict__ src_mask,
                                                       const int* __restrict__ tgt_mask,
                                                       const float* __restrict__ W,
                                                       const float* __restrict__ bias,
                                                       const float* __restrict__ g,
                                                       const float* __restrict__ be,
                                                       float* __restrict__ out,
                                                       float* __restrict__ mask_out) {
  const int bx = blockIdx.x;
  const int b  = bx >> 12;
  const int j  = bx & (TSRC - 1);
  const int t  = threadIdx.x;
  int s1 = 0, s2 = 0;
  for (int i = t; i < TSRC; i += 256) s1 += src_mask[(size_t)b * TSRC + i];
  for (int i = t; i < TTGT; i += 256) s2 += tgt_mask[(size_t)b * TTGT + i];
#pragma unroll
  for (int off = 32; off > 0; off >>= 1) { s1 += __shfl_down(s1, off); s2 += __shfl_down(s2, off); }
  __shared__ int ired[8];
  if ((t & 63) == 0) { ired[t >> 6] = s1; ired[4 + (t >> 6)] = s2; }
  __syncthreads();
  const int ss = ired[0] + ired[1] + ired[2] + ired[3];
  const int tg = ired[4] + ired[5] + ired[6] + ired[7];
  const bool valid = j < ss;
  int ii = 0;
  if (valid) {
    const int den = (ss > 0) ? ss : 1;
    ii = (int)(((long long)j * (long long)tg) / den);
    const int hi = ((tg > 1) ? tg : 1) - 1;
    if (ii > hi) ii = hi;
    if (ii < 0) ii = 0;
  }
  __shared__ float trow[CH];
  const float* tr = tgt + ((size_t)b * TTGT + ii) * CH;
  for (int i = t; i < CH; i += 256) trow[i] = valid ? tr[i] : 0.0f;
  __syncthreads();
  float4 v = make_float4(0.f, 0.f, 0.f, 0.f);
  if (valid) {
    float a0 = 0.f, a1 = 0.f, a2 = 0.f, a3 = 0.f;
    const float* w0 = W + (size_t)(4 * t + 0) * CH;
    const float* w1 = W + (size_t)(4 * t + 1) * CH;
    const float* w2 = W + (size_t)(4 * t + 2) * CH;
    const float* w3 = W + (size_t)(4 * t + 3) * CH;
    for (int k = 0; k < CH; ++k) {
      const float x = trow[k];
      a0 += x * w0[k]; a1 += x * w1[k]; a2 += x * w2[k]; a3 += x * w3[k];
    }
    v.x = a0 + bias[4 * t + 0];
    v.y = a1 + bias[4 * t + 1];
    v.z = a2 + bias[4 * t + 2];
    v.w = a3 + bias[4 * t + 3];
  }
  float s  = v.x + v.y + v.z + v.w;
  float sq = v.x * v.x + v.y * v.y + v.z * v.z + v.w * v.w;
#pragma unroll
  for (int off = 32; off > 0; off >>= 1) {
    s  += __shfl_down(s, off);
    sq += __shfl_down(sq, off);
  }
  __shared__ float red[8];
  __shared__ float stats[2];
  if ((t & 63) == 0) { red[t >> 6] = s; red[4 + (t >> 6)] = sq; }
  __syncthreads();
  if (t == 0) {
    const float S  = red[0] + red[1] + red[2] + red[3];
    const float Q  = red[4] + red[5] + red[6] + red[7];
    const float mu = S * (1.0f / CH);
    float var = Q * (1.0f / CH) - mu * mu;
    var = fmaxf(var, 0.0f);
    stats[0] = mu;
    stats[1] = rsqrtf(var + 1e-5f);
  }
  __syncthreads();
  const float mu = stats[0], rs = stats[1];
  const float4 gg = ((const float4*)g)[t];
  const float4 bb = ((const float4*)be)[t];
  float4 o;
  o.x = (v.x - mu) * rs * gg.x + bb.x;
  o.y = (v.y - mu) * rs * gg.y + bb.y;
  o.z = (v.z - mu) * rs * gg.z + bb.z;
  o.w = (v.w - mu) * rs * gg.w + bb.w;
  ((float4*)(out + ((size_t)b * TSRC + j) * CH))[t] = o;
  if (t == 0) mask_out[bx] = (float)src_mask[bx];
}

extern "C" void kernel_launch(void* const* d_in, const int* in_sizes, int n_in,
                              void* d_out, int out_size, void* d_ws, size_t ws_size,
                              hipStream_t stream) {
  (void)in_sizes; (void)n_in; (void)out_size;
  // setup_inputs order: src, src_mask, tgt, tgt_mask, conv_w, conv_b, ln_g, ln_b
  const int*   src_mask = (const int*)d_in[1];
  const float* tgt      = (const float*)d_in[2];
  const int*   tgt_mask = (const int*)d_in[3];
  const float* conv_w   = (const float*)d_in[4];
  const float* conv_b   = (const float*)d_in[5];
  const float* ln_g     = (const float*)d_in[6];
  const float* ln_b     = (const float*)d_in[7];

  float* out      = (float*)d_out;
  float* mask_out = out + (size_t)NB * TSRC * CH;   // second tuple element, as f32

  const size_t M       = (size_t)NB * TTGT;         // 16384 rows
  const size_t off_abf = 256;
  const size_t off_wbf = off_abf + M * CH * 2;      // +32 MiB
  const size_t off_y   = off_wbf + (size_t)CH * CH * 2;  // +2 MiB
  const size_t need2   = off_y + M * CH * 2;        // +32 MiB  => ~66 MiB
  const size_t need1   = 256 + M * CH * 4;          // ~64 MiB (f32 path)

  if (ws_size >= need2) {
    int*    sizes = (int*)d_ws;
    __bf16* Abf   = (__bf16*)((char*)d_ws + off_abf);
    __bf16* Wbf   = (__bf16*)((char*)d_ws + off_wbf);
    __bf16* y     = (__bf16*)((char*)d_ws + off_y);
    sizes_kernel<<<16, 256, 0, stream>>>(src_mask, tgt_mask, sizes);
    convert_kernel<<<NB * TTGT + CH, 256, 0, stream>>>(tgt, conv_w, sizes, src_mask,
                                                       Abf, Wbf, mask_out);
    gemm_kernel<<<dim3(CH / 128, (NB * TTGT) / 128), 256, 0, stream>>>(Abf, Wbf, conv_b,
                                                                       sizes, y);
    ln_kernel<<<2048, 256, 0, stream>>>(y, sizes, ln_g, ln_b, out);
  } else if (ws_size >= need1) {
    int*   sizes = (int*)d_ws;
    float* y     = (float*)((char*)d_ws + 256);
    sizes_kernel<<<16, 256, 0, stream>>>(src_mask, tgt_mask, sizes);
    gemm_f32_kernel<<<dim3(CH / 128, (NB * TTGT) / 128), 256, 0, stream>>>(tgt, conv_w, conv_b, sizes, y);
    ln_f32_kernel<<<NB * TSRC, 256, 0, stream>>>(y, sizes, src_mask, ln_g, ln_b, out, mask_out);
  } else {
    fallback_kernel<<<NB * TSRC, 256, 0, stream>>>(tgt, src_mask, tgt_mask, conv_w, conv_b,
                                                   ln_g, ln_b, out, mask_out);
  }
}

// Round 4
// 316.532 us; speedup vs baseline: 1.0701x; 1.0125x over previous
//
#include <hip/hip_runtime.h>

#define NB   8
#define TSRC 4096
#define TTGT 2048
#define CH   1024   // C_IN == C_OUT
#define BK   64

typedef __attribute__((ext_vector_type(4))) float  f32x4;
typedef __attribute__((ext_vector_type(8))) __bf16 bf16x8;
typedef __attribute__((ext_vector_type(4))) __bf16 bf16x4;

__device__ __forceinline__ void async16(const void* g, void* l) {
  __builtin_amdgcn_global_load_lds((const __attribute__((address_space(1))) void*)g,
                                   (__attribute__((address_space(3))) void*)l, 16, 0, 0);
}

// ---- kernel 1: fused prep = f32->bf16 convert (tgt + W) + ragged sizes + mask out --
// grid: [0, 17408)   convert one row per block (tgt rows then W rows)
//       [17408,17424) sizes: src_sizes -> sizes[0..7], tgt_sizes -> sizes[8..15]
//       [17424,17552) mask passthrough (32768 ints -> f32)
__global__ __launch_bounds__(256) void prep_kernel(const float* __restrict__ tgt,
                                                   const float* __restrict__ W,
                                                   const int* __restrict__ src_mask,
                                                   const int* __restrict__ tgt_mask,
                                                   __bf16* __restrict__ Abf,
                                                   __bf16* __restrict__ Wbf,
                                                   int* __restrict__ sizes,
                                                   float* __restrict__ mask_out) {
  const int bx = blockIdx.x;
  const int t  = threadIdx.x;
  const int NCONV = NB * TTGT + CH;          // 17408
  if (bx < NCONV) {
    const float* sp;
    __bf16* dp;
    if (bx < NB * TTGT) { sp = tgt + (size_t)bx * CH; dp = Abf + (size_t)bx * CH; }
    else { const int r = bx - NB * TTGT; sp = W + (size_t)r * CH; dp = Wbf + (size_t)r * CH; }
    const float4 v = ((const float4*)sp)[t];
    bf16x4 u = {(__bf16)v.x, (__bf16)v.y, (__bf16)v.z, (__bf16)v.w};
    *(bf16x4*)(dp + t * 4) = u;
  } else if (bx < NCONV + 16) {
    const int id = bx - NCONV;               // 0..7 src, 8..15 tgt
    const int b  = id & 7;
    const int* m = (id < 8) ? (src_mask + (size_t)b * TSRC) : (tgt_mask + (size_t)b * TTGT);
    const int T  = (id < 8) ? TSRC : TTGT;
    int s = 0;
    for (int i = t; i < T; i += 256) s += m[i];
#pragma unroll
    for (int off = 32; off > 0; off >>= 1) s += __shfl_down(s, off);
    __shared__ int red[4];
    if ((t & 63) == 0) red[t >> 6] = s;
    __syncthreads();
    if (t == 0) sizes[id] = red[0] + red[1] + red[2] + red[3];
  } else {
    const int i = (bx - (NCONV + 16)) * 256 + t;
    mask_out[i] = (float)src_mask[i];
  }
}

// ---- kernel 2: y = A @ W^T + bias, bf16 in/out, m97-style, XCD-swizzled grid -------
// A [M=NB*TTGT, K=CH] bf16 row-major; Wbf [N=CH, K=CH] bf16 row-major (NT GEMM).
// 128x128 tile, BK=64, global_load_lds width-16 staging, 4 waves in 2x2.
// Swizzle: bid%8 == Mt%8 -> all 8 N-blocks of one M-tile land on the same XCD,
// so the A-tile is fetched once into that XCD's L2; Wbf (2 MB) is L2-resident.
__global__ __launch_bounds__(256) void gemm_kernel(const __bf16* __restrict__ A,
                                                   const __bf16* __restrict__ Bw,
                                                   const float* __restrict__ bias,
                                                   const int* __restrict__ sizes,
                                                   __bf16* __restrict__ y) {
  const int bid = blockIdx.x;        // 0..1023
  const int Mt  = bid & 127;         // m-tile (bid%8 == Mt%8 -> XCD affinity)
  const int Nt  = bid >> 7;          // 0..7
  const int n0 = Nt * 128;
  const int m0 = Mt * 128;
  const int b  = m0 >> 11;
  const int t0 = m0 & (TTGT - 1);
  if (t0 >= sizes[8 + b]) return;    // rows never gathered

  __shared__ __bf16 As[128 * BK];    // 16 KB
  __shared__ __bf16 Bs[128 * BK];    // 16 KB

  const int tid  = threadIdx.x;
  const int lane = tid & 63;
  const int wave = tid >> 6;
  const int wm   = (wave >> 1) * 64;
  const int wn   = (wave & 1) * 64;
  const int lr   = lane & 15;
  const int quad = lane >> 4;

  // staging: thread t, issue q -> LDS elem q*2048 + t*8 (= row (q*32 + t/8), col (t%8)*8)
  const int srow = tid >> 3;
  const int scol = (tid & 7) * 8;
  const __bf16* gA = A  + ((size_t)(m0 + srow)) * CH + scol;
  const __bf16* gB = Bw + ((size_t)(n0 + srow)) * CH + scol;
  __bf16* lA = As + tid * 8;
  __bf16* lB = Bs + tid * 8;

  f32x4 acc[4][4];
  const f32x4 z = {0.f, 0.f, 0.f, 0.f};
#pragma unroll
  for (int i = 0; i < 4; ++i)
#pragma unroll
    for (int j = 0; j < 4; ++j) acc[i][j] = z;

  for (int kb = 0; kb < CH; kb += BK) {
#pragma unroll
    for (int q = 0; q < 4; ++q) {
      async16(gA + (size_t)q * 32 * CH + kb, lA + q * 2048);
      async16(gB + (size_t)q * 32 * CH + kb, lB + q * 2048);
    }
    __syncthreads();
#pragma unroll
    for (int ko = 0; ko < 2; ++ko) {
      bf16x8 af[4], bf[4];
#pragma unroll
      for (int i = 0; i < 4; ++i)
        af[i] = *(const bf16x8*)(As + (wm + i * 16 + lr) * BK + ko * 32 + quad * 8);
#pragma unroll
      for (int j = 0; j < 4; ++j)
        bf[j] = *(const bf16x8*)(Bs + (wn + j * 16 + lr) * BK + ko * 32 + quad * 8);
#pragma unroll
      for (int i = 0; i < 4; ++i)
#pragma unroll
        for (int j = 0; j < 4; ++j)
          acc[i][j] = __builtin_amdgcn_mfma_f32_16x16x32_bf16(af[i], bf[j], acc[i][j], 0, 0, 0);
    }
    __syncthreads();
  }

  // epilogue: C/D layout col = lane&15, row = quad*4 + reg; store bf16
#pragma unroll
  for (int i = 0; i < 4; ++i) {
    const int mrow = m0 + wm + i * 16 + quad * 4;
#pragma unroll
    for (int j = 0; j < 4; ++j) {
      const int ncol = n0 + wn + j * 16 + lr;
      const float bv = bias[ncol];
      __bf16* yp = y + (size_t)mrow * CH + ncol;
#pragma unroll
      for (int r = 0; r < 4; ++r) yp[(size_t)r * CH] = (__bf16)(acc[i][j][r] + bv);
    }
  }
}

// ---- kernel 3: gather + LayerNorm, wave-per-row (no barriers) ----------------------
__global__ __launch_bounds__(256) void ln_kernel(const __bf16* __restrict__ y,
                                                 const int* __restrict__ sizes,
                                                 const float* __restrict__ g,
                                                 const float* __restrict__ be,
                                                 float* __restrict__ out) {
  const int wid = (blockIdx.x * 256 + threadIdx.x) >> 6;  // 0..8191
  const int l   = threadIdx.x & 63;
#pragma unroll
  for (int rr = 0; rr < 4; ++rr) {
    const int row = wid + rr * 8192;        // 0..32767
    const int b   = row >> 12;
    const int j   = row & (TSRC - 1);
    const int ss  = sizes[b];
    const int tg  = sizes[8 + b];
    float v[16];
    if (j < ss) {
      const int den = (ss > 0) ? ss : 1;
      int ii = (int)(((long long)j * (long long)tg) / den);
      const int hi = ((tg > 1) ? tg : 1) - 1;
      ii = (ii > hi) ? hi : ((ii < 0) ? 0 : ii);
      const __bf16* yr = y + ((size_t)b * TTGT + ii) * CH;
      const bf16x8 u0 = *(const bf16x8*)(yr + l * 8);
      const bf16x8 u1 = *(const bf16x8*)(yr + 512 + l * 8);
#pragma unroll
      for (int k = 0; k < 8; ++k) { v[k] = (float)u0[k]; v[8 + k] = (float)u1[k]; }
    } else {
#pragma unroll
      for (int k = 0; k < 16; ++k) v[k] = 0.f;
    }
    float s = 0.f, q = 0.f;
#pragma unroll
    for (int k = 0; k < 16; ++k) { s += v[k]; q += v[k] * v[k]; }
#pragma unroll
    for (int off = 32; off > 0; off >>= 1) {
      s += __shfl_xor(s, off);
      q += __shfl_xor(q, off);
    }
    const float mu = s * (1.0f / CH);
    float var = q * (1.0f / CH) - mu * mu;
    var = fmaxf(var, 0.0f);
    const float rs = rsqrtf(var + 1e-5f);
    float* orow = out + (size_t)row * CH;
#pragma unroll
    for (int h = 0; h < 2; ++h) {
      const int base = h * 512 + l * 8;
      const float4 g0 = *(const float4*)(g + base);
      const float4 g1 = *(const float4*)(g + base + 4);
      const float4 b0 = *(const float4*)(be + base);
      const float4 b1 = *(const float4*)(be + base + 4);
      float4 o0, o1;
      o0.x = (v[h * 8 + 0] - mu) * rs * g0.x + b0.x;
      o0.y = (v[h * 8 + 1] - mu) * rs * g0.y + b0.y;
      o0.z = (v[h * 8 + 2] - mu) * rs * g0.z + b0.z;
      o0.w = (v[h * 8 + 3] - mu) * rs * g0.w + b0.w;
      o1.x = (v[h * 8 + 4] - mu) * rs * g1.x + b1.x;
      o1.y = (v[h * 8 + 5] - mu) * rs * g1.y + b1.y;
      o1.z = (v[h * 8 + 6] - mu) * rs * g1.z + b1.z;
      o1.w = (v[h * 8 + 7] - mu) * rs * g1.w + b1.w;
      *(float4*)(orow + base)     = o0;
      *(float4*)(orow + base + 4) = o1;
    }
  }
}

// ---------------- fallback: fully self-contained, no workspace needed ---------------
__global__ __launch_bounds__(256) void fallback_kernel(const float* __restrict__ tgt,
                                                       const int* __restrict__ src_mask,
                                                       const int* __restrict__ tgt_mask,
                                                       const float* __restrict__ W,
                                                       const float* __restrict__ bias,
                                                       const float* __restrict__ g,
                                                       const float* __restrict__ be,
                                                       float* __restrict__ out,
                                                       float* __restrict__ mask_out) {
  const int bx = blockIdx.x;
  const int b  = bx >> 12;
  const int j  = bx & (TSRC - 1);
  const int t  = threadIdx.x;
  int s1 = 0, s2 = 0;
  for (int i = t; i < TSRC; i += 256) s1 += src_mask[(size_t)b * TSRC + i];
  for (int i = t; i < TTGT; i += 256) s2 += tgt_mask[(size_t)b * TTGT + i];
#pragma unroll
  for (int off = 32; off > 0; off >>= 1) { s1 += __shfl_down(s1, off); s2 += __shfl_down(s2, off); }
  __shared__ int ired[8];
  if ((t & 63) == 0) { ired[t >> 6] = s1; ired[4 + (t >> 6)] = s2; }
  __syncthreads();
  const int ss = ired[0] + ired[1] + ired[2] + ired[3];
  const int tg = ired[4] + ired[5] + ired[6] + ired[7];
  const bool valid = j < ss;
  int ii = 0;
  if (valid) {
    const int den = (ss > 0) ? ss : 1;
    ii = (int)(((long long)j * (long long)tg) / den);
    const int hi = ((tg > 1) ? tg : 1) - 1;
    if (ii > hi) ii = hi;
    if (ii < 0) ii = 0;
  }
  __shared__ float trow[CH];
  const float* tr = tgt + ((size_t)b * TTGT + ii) * CH;
  for (int i = t; i < CH; i += 256) trow[i] = valid ? tr[i] : 0.0f;
  __syncthreads();
  float4 v = make_float4(0.f, 0.f, 0.f, 0.f);
  if (valid) {
    float a0 = 0.f, a1 = 0.f, a2 = 0.f, a3 = 0.f;
    const float* w0 = W + (size_t)(4 * t + 0) * CH;
    const float* w1 = W + (size_t)(4 * t + 1) * CH;
    const float* w2 = W + (size_t)(4 * t + 2) * CH;
    const float* w3 = W + (size_t)(4 * t + 3) * CH;
    for (int k = 0; k < CH; ++k) {
      const float x = trow[k];
      a0 += x * w0[k]; a1 += x * w1[k]; a2 += x * w2[k]; a3 += x * w3[k];
    }
    v.x = a0 + bias[4 * t + 0];
    v.y = a1 + bias[4 * t + 1];
    v.z = a2 + bias[4 * t + 2];
    v.w = a3 + bias[4 * t + 3];
  }
  float s  = v.x + v.y + v.z + v.w;
  float sq = v.x * v.x + v.y * v.y + v.z * v.z + v.w * v.w;
#pragma unroll
  for (int off = 32; off > 0; off >>= 1) {
    s  += __shfl_down(s, off);
    sq += __shfl_down(sq, off);
  }
  __shared__ float red[8];
  __shared__ float stats[2];
  if ((t & 63) == 0) { red[t >> 6] = s; red[4 + (t >> 6)] = sq; }
  __syncthreads();
  if (t == 0) {
    const float S  = red[0] + red[1] + red[2] + red[3];
    const float Q  = red[4] + red[5] + red[6] + red[7];
    const float mu = S * (1.0f / CH);
    float var = Q * (1.0f / CH) - mu * mu;
    var = fmaxf(var, 0.0f);
    stats[0] = mu;
    stats[1] = rsqrtf(var + 1e-5f);
  }
  __syncthreads();
  const float mu = stats[0], rs = stats[1];
  const float4 gg = ((const float4*)g)[t];
  const float4 bb = ((const float4*)be)[t];
  float4 o;
  o.x = (v.x - mu) * rs * gg.x + bb.x;
  o.y = (v.y - mu) * rs * gg.y + bb.y;
  o.z = (v.z - mu) * rs * gg.z + bb.z;
  o.w = (v.w - mu) * rs * gg.w + bb.w;
  ((float4*)(out + ((size_t)b * TSRC + j) * CH))[t] = o;
  if (t == 0) mask_out[bx] = (float)src_mask[bx];
}

extern "C" void kernel_launch(void* const* d_in, const int* in_sizes, int n_in,
                              void* d_out, int out_size, void* d_ws, size_t ws_size,
                              hipStream_t stream) {
  (void)in_sizes; (void)n_in; (void)out_size;
  // setup_inputs order: src, src_mask, tgt, tgt_mask, conv_w, conv_b, ln_g, ln_b
  const int*   src_mask = (const int*)d_in[1];
  const float* tgt      = (const float*)d_in[2];
  const int*   tgt_mask = (const int*)d_in[3];
  const float* conv_w   = (const float*)d_in[4];
  const float* conv_b   = (const float*)d_in[5];
  const float* ln_g     = (const float*)d_in[6];
  const float* ln_b     = (const float*)d_in[7];

  float* out      = (float*)d_out;
  float* mask_out = out + (size_t)NB * TSRC * CH;   // second tuple element, as f32

  const size_t M       = (size_t)NB * TTGT;              // 16384 rows
  const size_t off_abf = 256;
  const size_t off_wbf = off_abf + M * CH * 2;           // +32 MiB
  const size_t off_y   = off_wbf + (size_t)CH * CH * 2;  // +2 MiB
  const size_t need    = off_y + M * CH * 2;             // +32 MiB => ~66 MiB

  if (ws_size >= need) {
    int*    sizes = (int*)d_ws;
    __bf16* Abf   = (__bf16*)((char*)d_ws + off_abf);
    __bf16* Wbf   = (__bf16*)((char*)d_ws + off_wbf);
    __bf16* y     = (__bf16*)((char*)d_ws + off_y);
    prep_kernel<<<NB * TTGT + CH + 16 + 128, 256, 0, stream>>>(tgt, conv_w, src_mask, tgt_mask,
                                                               Abf, Wbf, sizes, mask_out);
    gemm_kernel<<<1024, 256, 0, stream>>>(Abf, Wbf, conv_b, sizes, y);
    ln_kernel<<<2048, 256, 0, stream>>>(y, sizes, ln_g, ln_b, out);
  } else {
    fallback_kernel<<<NB * TSRC, 256, 0, stream>>>(tgt, src_mask, tgt_mask, conv_w, conv_b,
                                                   ln_g, ln_b, out, mask_out);
  }
}